// Round 5
// baseline (292.109 us; speedup 1.0000x reference)
//
#include <hip/hip_runtime.h>
#include <stdint.h>

// AttentionGate fused kernel, MI355X gfx950. Inputs fp32.
//
// Prepass: Wx, Wg fp32 -> bf16 in fragment-chunk layout [it][n][32k]; main
// kernel reads B-operand MFMA fragments directly from global (L2-hot).
// Main kernel: 2048 blocks x 32 px x 256 out. A (x,g) tiles double-buffered
// bf16 in LDS; DEPTH-2 register prefetch: loads for it+2 issued at iter it,
// ds_write'd at iter it+1 -> loads outstanding across barriers continuously
// (R4 was same-iter consume -> 27% memory duty cycle, 2.07 TB/s).
// Epilogue: bias+relu in regs; LN + psi fused to per-pixel (s,ss,t)
// reductions -> sigmoid -> out = psi * x (x re-read, L3-hot).

typedef __bf16 bf16x8 __attribute__((ext_vector_type(8)));
typedef float f32x4 __attribute__((ext_vector_type(4)));

#define STR 40            // LDS row stride in shorts (80 B rows)
#define LN_EPS 1e-5f

__device__ __forceinline__ uint16_t f2b(float f) {
    union { float f; uint32_t i; } v; v.f = f;
    uint32_t x = v.i;
    return (uint16_t)((x + 0x7FFFu + ((x >> 16) & 1u)) >> 16);  // RNE
}

struct EpiShared {
    float red[3][4][32];   // s, ss, t partials: [value][wave][pixel]
    float psi[32];
    float cpart[8];        // per-wave partials: sumA (0..3), sumB (4..7)
};

union ALds {
    uint16_t a[2][2][32 * STR];   // [buf][tensor: 0=x 1=g][px*STR + k]  10 KiB
    EpiShared e;
};

// ---- prepass: W fp32 -> bf16 chunk layout: dst[it*8192 + n*32 + kk] ----
__global__ void wconv_kernel(const float* __restrict__ Wx, const float* __restrict__ Wg,
                             uint16_t* __restrict__ ox, uint16_t* __restrict__ og) {
    const int i  = blockIdx.x * 256 + threadIdx.x;   // 64 blocks -> 16384
    const int n  = i >> 6;
    const int k4 = (i & 63) * 4;
    const int it = k4 >> 5;
    const int kk = k4 & 31;
    const int dst = it * 8192 + n * 32 + kk;
    const float4 a = *(const float4*)&Wx[n * 256 + k4];
    const float4 b = *(const float4*)&Wg[n * 256 + k4];
    uint2 pa, pb;
    pa.x = (uint32_t)f2b(a.x) | ((uint32_t)f2b(a.y) << 16);
    pa.y = (uint32_t)f2b(a.z) | ((uint32_t)f2b(a.w) << 16);
    pb.x = (uint32_t)f2b(b.x) | ((uint32_t)f2b(b.y) << 16);
    pb.y = (uint32_t)f2b(b.z) | ((uint32_t)f2b(b.w) << 16);
    *(uint2*)&ox[dst] = pa;
    *(uint2*)&og[dst] = pb;
}

__device__ __forceinline__ void stage_load(float av[8], const float* __restrict__ Asrc,
                                           size_t abase, int c0, int px) {
    #pragma unroll
    for (int c = 0; c < 8; ++c)
        av[c] = Asrc[abase + (size_t)(c0 + c) * 4096 + px];
}

__device__ __forceinline__ void stage_store(const float av[8], uint16_t* dst) {
    uint4 w;
    w.x = (uint32_t)f2b(av[0]) | ((uint32_t)f2b(av[1]) << 16);
    w.y = (uint32_t)f2b(av[2]) | ((uint32_t)f2b(av[3]) << 16);
    w.z = (uint32_t)f2b(av[4]) | ((uint32_t)f2b(av[5]) << 16);
    w.w = (uint32_t)f2b(av[6]) | ((uint32_t)f2b(av[7]) << 16);
    *(uint4*)dst = w;   // ds_write_b128, 2-way (free) conflicts
}

__global__ __launch_bounds__(256, 6) void attgate_kernel(
    const float* __restrict__ x,
    const float* __restrict__ g,
    const uint16_t* __restrict__ Wxb,   // bf16 chunk layout [8][256][32]
    const uint16_t* __restrict__ Wgb,
    const float* __restrict__ Wpsi,
    const float* __restrict__ gamma,
    const float* __restrict__ beta,
    const float* __restrict__ bxg,
    const float* __restrict__ bpsi,
    float* __restrict__ out)
{
    __shared__ __align__(16) ALds u;

    const int t    = threadIdx.x;
    const int lane = t & 63;
    const int wv   = t >> 6;        // wave 0..3 -> output-channel slice
    const int ln   = lane & 15;     // tile row/col index
    const int q    = lane >> 4;     // quad 0..3 (k-quad)

    const int gp0  = blockIdx.x * 32;            // global pixel base
    const int b    = gp0 >> 12;                  // batch (4096 px per image)
    const int pix0 = gp0 & 4095;
    const size_t xbase = (size_t)b * (256 * 4096) + pix0;  // + c*4096 + p

    f32x4 acc[2][4];
    #pragma unroll
    for (int i = 0; i < 2; ++i)
        #pragma unroll
        for (int j = 0; j < 4; ++j)
            acc[i][j] = (f32x4){0.f, 0.f, 0.f, 0.f};

    // ---- A staging: thread = 1 px x 8 ch. 128 threads per tensor. ----
    const int at  = t & 127;
    const int px  = at & 31;
    const int c0  = (at >> 5) * 8;  // 0,8,16,24
    const float* Asrc = (t < 128) ? x : g;
    const int tens    = (t < 128) ? 0 : 1;
    uint16_t* dst0 = &u.a[0][tens][px * STR + c0];
    uint16_t* dst1 = &u.a[1][tens][px * STR + c0];
    const size_t abase = xbase + (size_t)c0 * 4096 + px;   // + k0*4096 per iter

    const int fro = wv * 64 + ln;   // W fragment row base

    float avA[8], avB[8];
    stage_load(avA, Asrc, abase, 0, 0);                 // it0 (c0/px folded in abase)
    stage_store(avA, dst0);
    stage_load(avA, Asrc, abase + (size_t)32 * 4096, 0, 0);   // it1

    #pragma unroll 1
    for (int it = 0; it < 8; it += 2) {
        // ================= even phase: buf0, W(it), prefetch it+2 ==========
        __syncthreads();
        {
            const uint16_t* Wxi = Wxb + it * 8192;
            const uint16_t* Wgi = Wgb + it * 8192;
            bf16x8 bx[4];
            #pragma unroll
            for (int nt = 0; nt < 4; ++nt)
                bx[nt] = *(const bf16x8*)&Wxi[(fro + nt * 16) * 32 + q * 8];

            if (it + 2 < 8)
                stage_load(avB, Asrc, abase + (size_t)((it + 2) * 32) * 4096, 0, 0);

            bf16x8 af[2];
            #pragma unroll
            for (int mt = 0; mt < 2; ++mt)
                af[mt] = *(const bf16x8*)&u.a[0][0][(mt * 16 + ln) * STR + q * 8];
            #pragma unroll
            for (int mt = 0; mt < 2; ++mt)
                #pragma unroll
                for (int nt = 0; nt < 4; ++nt)
                    acc[mt][nt] = __builtin_amdgcn_mfma_f32_16x16x32_bf16(af[mt], bx[nt], acc[mt][nt], 0, 0, 0);

            bf16x8 bg[4];
            #pragma unroll
            for (int nt = 0; nt < 4; ++nt)
                bg[nt] = *(const bf16x8*)&Wgi[(fro + nt * 16) * 32 + q * 8];
            #pragma unroll
            for (int mt = 0; mt < 2; ++mt)
                af[mt] = *(const bf16x8*)&u.a[0][1][(mt * 16 + ln) * STR + q * 8];
            #pragma unroll
            for (int mt = 0; mt < 2; ++mt)
                #pragma unroll
                for (int nt = 0; nt < 4; ++nt)
                    acc[mt][nt] = __builtin_amdgcn_mfma_f32_16x16x32_bf16(af[mt], bg[nt], acc[mt][nt], 0, 0, 0);

            stage_store(avA, dst1);        // it+1 data (loaded a full iter ago)
        }
        // ================= odd phase: buf1, W(it+1), prefetch it+3 =========
        __syncthreads();
        {
            const uint16_t* Wxi = Wxb + (it + 1) * 8192;
            const uint16_t* Wgi = Wgb + (it + 1) * 8192;
            bf16x8 bx[4];
            #pragma unroll
            for (int nt = 0; nt < 4; ++nt)
                bx[nt] = *(const bf16x8*)&Wxi[(fro + nt * 16) * 32 + q * 8];

            if (it + 3 < 8)
                stage_load(avA, Asrc, abase + (size_t)((it + 3) * 32) * 4096, 0, 0);

            bf16x8 af[2];
            #pragma unroll
            for (int mt = 0; mt < 2; ++mt)
                af[mt] = *(const bf16x8*)&u.a[1][0][(mt * 16 + ln) * STR + q * 8];
            #pragma unroll
            for (int mt = 0; mt < 2; ++mt)
                #pragma unroll
                for (int nt = 0; nt < 4; ++nt)
                    acc[mt][nt] = __builtin_amdgcn_mfma_f32_16x16x32_bf16(af[mt], bx[nt], acc[mt][nt], 0, 0, 0);

            bf16x8 bg[4];
            #pragma unroll
            for (int nt = 0; nt < 4; ++nt)
                bg[nt] = *(const bf16x8*)&Wgi[(fro + nt * 16) * 32 + q * 8];
            #pragma unroll
            for (int mt = 0; mt < 2; ++mt)
                af[mt] = *(const bf16x8*)&u.a[1][1][(mt * 16 + ln) * STR + q * 8];
            #pragma unroll
            for (int mt = 0; mt < 2; ++mt)
                #pragma unroll
                for (int nt = 0; nt < 4; ++nt)
                    acc[mt][nt] = __builtin_amdgcn_mfma_f32_16x16x32_bf16(af[mt], bg[nt], acc[mt][nt], 0, 0, 0);

            if (it + 2 < 8)
                stage_store(avB, dst0);    // it+2 data
        }
    }

    __syncthreads();   // A LDS now reusable as epilogue scratch

    // ---- block-wide constants: sumA = sum(Wpsi*gamma), sumB = sum(Wpsi*beta) ----
    {
        float a  = Wpsi[t] * gamma[t];
        float bb = Wpsi[t] * beta[t];
        #pragma unroll
        for (int off = 32; off; off >>= 1) {
            a  += __shfl_xor(a, off, 64);
            bb += __shfl_xor(bb, off, 64);
        }
        if (lane == 0) { u.e.cpart[wv] = a; u.e.cpart[4 + wv] = bb; }
    }

    // per-lane channel constants (channel o = wv*64 + nt*16 + ln)
    float biasv[4], Ac[4];
    #pragma unroll
    for (int nt = 0; nt < 4; ++nt) {
        const int o = wv * 64 + nt * 16 + ln;
        biasv[nt] = bxg[o];
        Ac[nt]    = Wpsi[o] * gamma[o];
    }
    __syncthreads();
    const float sumA = u.e.cpart[0] + u.e.cpart[1] + u.e.cpart[2] + u.e.cpart[3];
    const float sumB = u.e.cpart[4] + u.e.cpart[5] + u.e.cpart[6] + u.e.cpart[7];

    // ---- per-pixel reductions: s, ss, t over this wave's 64 channels ----
    #pragma unroll
    for (int mt = 0; mt < 2; ++mt) {
        #pragma unroll
        for (int r = 0; r < 4; ++r) {
            float s = 0.f, ss = 0.f, tt = 0.f;
            #pragma unroll
            for (int nt = 0; nt < 4; ++nt) {
                float v = acc[mt][nt][r] + biasv[nt];
                v = fmaxf(v, 0.f);               // relu
                s += v; ss += v * v; tt += Ac[nt] * v;
            }
            #pragma unroll
            for (int off = 1; off < 16; off <<= 1) {   // reduce 16 lanes (n dim)
                s  += __shfl_xor(s,  off, 64);
                ss += __shfl_xor(ss, off, 64);
                tt += __shfl_xor(tt, off, 64);
            }
            if (ln == 0) {
                const int pix = mt * 16 + q * 4 + r;   // C/D row = q*4 + reg
                u.e.red[0][wv][pix] = s;
                u.e.red[1][wv][pix] = ss;
                u.e.red[2][wv][pix] = tt;
            }
        }
    }
    __syncthreads();

    // ---- LN + psi dot + sigmoid (one thread per pixel) ----
    if (t < 32) {
        const float s  = u.e.red[0][0][t] + u.e.red[0][1][t] + u.e.red[0][2][t] + u.e.red[0][3][t];
        const float ss = u.e.red[1][0][t] + u.e.red[1][1][t] + u.e.red[1][2][t] + u.e.red[1][3][t];
        const float tt = u.e.red[2][0][t] + u.e.red[2][1][t] + u.e.red[2][2][t] + u.e.red[2][3][t];
        const float mu   = s * (1.f / 256.f);
        const float var  = ss * (1.f / 256.f) - mu * mu;
        const float rstd = rsqrtf(var + LN_EPS);
        const float z    = rstd * (tt - mu * sumA) + sumB + bpsi[0];
        u.e.psi[t] = 1.f / (1.f + __expf(-z));
    }
    __syncthreads();

    // ---- out[c][p] = psi[p] * x[c][p], 8 passes of float4 per thread ----
    const int pc = (t & 7) * 4;
    const float p0 = u.e.psi[pc], p1 = u.e.psi[pc + 1], p2 = u.e.psi[pc + 2], p3 = u.e.psi[pc + 3];
    const int crow = t >> 3;     // 0..31
    #pragma unroll
    for (int pass = 0; pass < 8; ++pass) {
        const int c = pass * 32 + crow;
        const size_t off = xbase + (size_t)c * 4096 + pc;
        const float4 d = *(const float4*)&x[off];
        float4 o;
        o.x = d.x * p0; o.y = d.y * p1; o.z = d.z * p2; o.w = d.w * p3;
        *(float4*)&out[off] = o;
    }
}

extern "C" void kernel_launch(void* const* d_in, const int* in_sizes, int n_in,
                              void* d_out, int out_size, void* d_ws, size_t ws_size,
                              hipStream_t stream) {
    const float* x    = (const float*)d_in[0];
    const float* g    = (const float*)d_in[1];
    const float* Wx   = (const float*)d_in[2];
    const float* Wg   = (const float*)d_in[3];
    const float* Wpsi = (const float*)d_in[4];
    const float* gam  = (const float*)d_in[5];
    const float* bet  = (const float*)d_in[6];
    const float* bxg  = (const float*)d_in[7];
    const float* bpsi = (const float*)d_in[8];
    float* out        = (float*)d_out;

    uint16_t* Wxb = (uint16_t*)d_ws;                 // 131072 B
    uint16_t* Wgb = (uint16_t*)((char*)d_ws + 131072);

    wconv_kernel<<<dim3(64), dim3(256), 0, stream>>>(Wx, Wg, Wxb, Wgb);
    attgate_kernel<<<dim3(2048), dim3(256), 0, stream>>>(
        x, g, Wxb, Wgb, Wpsi, gam, bet, bxg, bpsi, out);
}